// Round 6
// baseline (22785.977 us; speedup 1.0000x reference)
//
#include <hip/hip_runtime.h>
#include <stdint.h>

#define N_PTS   65536
#define N_GRP   1024
#define K_NB    32
#define F_DIM   64

// ---- F1: fast FPS (8 same-XCD blocks, L2-local sync), deadline-capped ----
#define F1_BLOCKS 64
#define F1_THR    1024
#define F1_NP     8
#define F1_P      (N_PTS / (F1_NP * F1_THR))   // 8 pts/thread
#define RING      16
#define DEADLINE_TICKS 2000000ull              // ~20-80ms depending on RTC freq

// ---- F2: rescue FPS (R1-proven 16-block agent-scope design) ----
#define F2_BLOCKS 16
#define F2_THR    512
#define F2_TT     (F2_BLOCKS*F2_THR)           // 8192
#define F2_P      (N_PTS / F2_TT)              // 8

// ---------- helpers ----------
__device__ __forceinline__ unsigned long long packMinKey(float v, unsigned int idx) {
  unsigned int b = __float_as_uint(v);
  b = (b & 0x80000000u) ? ~b : (b | 0x80000000u);
  return ((unsigned long long)b << 32) | idx;
}
__device__ __forceinline__ float unpackMinVal(unsigned long long k) {
  unsigned int b = (unsigned int)(k >> 32);
  b = (b & 0x80000000u) ? (b & 0x7FFFFFFFu) : ~b;
  return __uint_as_float(b);
}
__device__ __forceinline__ void st_sc0_u64(unsigned long long* p, unsigned long long v) {
  asm volatile("global_store_dwordx2 %0, %1, off sc0\n\ts_waitcnt vmcnt(0)"
               :: "v"((unsigned long long)(uintptr_t)p), "v"(v) : "memory");
}
__device__ __forceinline__ unsigned long long ld_sc0_u64(const unsigned long long* p) {
  unsigned long long v;
  asm volatile("global_load_dwordx2 %0, %1, off sc0\n\ts_waitcnt vmcnt(0)"
               : "=v"(v) : "v"((unsigned long long)(uintptr_t)p) : "memory");
  return v;
}
__device__ __forceinline__ int get_xcc_id() {
  int x;
  asm("s_getreg_b32 %0, hwreg(HW_REG_XCC_ID)" : "=s"(x));
  return x & 7;
}

// ctrl u32 layout: [0..7] per-XCD counts, [8] winner(xcd+1), [9] fail, [10] success
__global__ void __launch_bounds__(F1_THR)
fps_fast_kernel(const float* __restrict__ x, unsigned int* __restrict__ ctrl,
                unsigned long long* __restrict__ ring, float* __restrict__ centers)
{
  const int tid = threadIdx.x, lane = tid & 63, wid = tid >> 6;
  __shared__ int s_stat, s_pid;     // stat: 0=bystander 1=participant 2=reg-timeout
  __shared__ unsigned long long red[F1_THR/64];
  __shared__ unsigned long long winbuf;
  const unsigned long long t0 = __builtin_amdgcn_s_memrealtime();

  if (tid == 0) {
    const int xcc = get_xcc_id();
    const unsigned rank = __hip_atomic_fetch_add(&ctrl[xcc], 1u,
                              __ATOMIC_RELAXED, __HIP_MEMORY_SCOPE_AGENT);
    if (rank == F1_NP - 1) {          // my XCD just filled: try to claim
      unsigned exp = 0;
      __hip_atomic_compare_exchange_strong(&ctrl[8], &exp, (unsigned)(xcc + 1),
          __ATOMIC_ACQ_REL, __ATOMIC_RELAXED, __HIP_MEMORY_SCOPE_AGENT);
    }
    unsigned w = 0;
    for (;;) {
      w = __hip_atomic_load(&ctrl[8], __ATOMIC_ACQUIRE, __HIP_MEMORY_SCOPE_AGENT);
      if (w) break;
      if (__builtin_amdgcn_s_memrealtime() - t0 > DEADLINE_TICKS) break;
      __builtin_amdgcn_s_sleep(2);
    }
    s_stat = (w == 0) ? 2 : (((w == (unsigned)(xcc+1)) && (rank < F1_NP)) ? 1 : 0);
    s_pid  = (int)rank;
  }
  __syncthreads();
  const int stat = s_stat;
  if (stat == 2) {    // winner never set (shouldn't happen): flag fail, rescue will run
    if (tid == 0) __hip_atomic_store(&ctrl[9], 1u, __ATOMIC_RELEASE, __HIP_MEMORY_SCOPE_AGENT);
    return;
  }
  if (stat == 0) return;
  const int pid = s_pid;

  const int base = pid * (F1_THR * F1_P);
  float px[F1_P], py[F1_P], pz[F1_P], d[F1_P];
#pragma unroll
  for (int k = 0; k < F1_P; ++k) {
    int p = base + k*F1_THR + tid;
    px[k] = x[p*3+0]; py[k] = x[p*3+1]; pz[k] = x[p*3+2];
    d[k] = 1e10f;
  }
  float cx = x[0], cy = x[1], cz = x[2];
  if (pid == 0 && tid == 0) { centers[0]=cx; centers[1]=cy; centers[2]=cz; }

  for (int r = 1; r < N_GRP; ++r) {
    float bd = -1.0f; unsigned bi = 0;
#pragma unroll
    for (int k = 0; k < F1_P; ++k) {
      float e0 = px[k]-cx, e1 = py[k]-cy, e2 = pz[k]-cz;
      float dist = fmaf(e2,e2, fmaf(e1,e1, e0*e0));     // same fma chain as proven rounds
      float dn = fminf(d[k], dist);
      d[k] = dn;
      if (dn > bd) { bd = dn; bi = (unsigned)(base + k*F1_THR + tid); }
    }
    // key: [63:32]=dist bits, [31:16]=0xFFFF-idx (idx asc on tie), [15:0]=round tag
    unsigned long long key = ((unsigned long long)__float_as_uint(bd) << 32)
                           | ((unsigned long long)(0xFFFFu - bi) << 16)
                           | (unsigned long long)(unsigned)r;
#pragma unroll
    for (int off = 32; off; off >>= 1) {
      unsigned long long o = __shfl_xor(key, off);
      if (o > key) key = o;
    }
    if (lane == 0) red[wid] = key;
    __syncthreads();                                    // barrier 1
    if (wid == 0) {
      unsigned long long kb = (lane < F1_THR/64) ? red[lane] : 0ull;
#pragma unroll
      for (int off = 1; off < F1_THR/64; off <<= 1) {
        unsigned long long o = __shfl_xor(kb, off);
        if (o > kb) kb = o;
      }
      unsigned long long* rs = &ring[(size_t)(r & (RING-1)) * F1_NP];
      if (lane == 0) st_sc0_u64(&rs[pid], kb);
      unsigned long long kk = 0; bool ok = true;
      if (lane < F1_NP) {                               // tag-validated L2-local poll
        int it = 0;
        for (;;) {
          kk = ld_sc0_u64(&rs[lane]);
          if ((kk & 0xFFFFull) == (unsigned long long)(unsigned)r) break;
          if (((++it) & 63) == 0 &&
              __builtin_amdgcn_s_memrealtime() - t0 > DEADLINE_TICKS) { ok = false; break; }
        }
      }
      const bool okall = __all(ok);
#pragma unroll
      for (int off = 1; off < F1_NP; off <<= 1) {
        unsigned long long o = __shfl_xor(kk, off);
        if (o > kk) kk = o;
      }
      if (lane == 0) winbuf = okall ? kk : 0ull;        // 0 = poison (real keys have tag r>=1)
    }
    __syncthreads();                                    // barrier 2
    const unsigned long long w = winbuf;
    if (w == 0ull) {                                    // deadline hit: flag fail, bail out
      if (tid == 0) __hip_atomic_store(&ctrl[9], 1u, __ATOMIC_RELEASE, __HIP_MEMORY_SCOPE_AGENT);
      return;
    }
    const int widx = (int)(0xFFFFu - (unsigned)((w >> 16) & 0xFFFFull));
    cx = x[widx*3+0]; cy = x[widx*3+1]; cz = x[widx*3+2];
    if (pid == 0 && tid == 0) {
      centers[r*3+0]=cx; centers[r*3+1]=cy; centers[r*3+2]=cz;
    }
  }
  if (pid == 0 && tid == 0)
    __hip_atomic_store(&ctrl[10], 1u, __ATOMIC_RELEASE, __HIP_MEMORY_SCOPE_AGENT);
}

// ---------- F2: rescue FPS — R1-proven design, skips if F1 succeeded ----------
__global__ void __launch_bounds__(F2_THR)
fps_safe_kernel(const float* __restrict__ x, unsigned long long* __restrict__ slots,
                unsigned int* __restrict__ cnts, float* __restrict__ centers,
                const unsigned int* __restrict__ ctrl)
{
  __shared__ int s_skip;
  __shared__ unsigned long long red[F2_THR/64];
  if (threadIdx.x == 0) {
    unsigned s = __hip_atomic_load(&ctrl[10], __ATOMIC_ACQUIRE, __HIP_MEMORY_SCOPE_AGENT);
    unsigned f = __hip_atomic_load(&ctrl[9],  __ATOMIC_ACQUIRE, __HIP_MEMORY_SCOPE_AGENT);
    s_skip = (s == 1u && f == 0u) ? 1 : 0;
  }
  __syncthreads();
  if (s_skip) return;

  const int t = blockIdx.x * F2_THR + threadIdx.x;
  float px[F2_P], py[F2_P], pz[F2_P], d[F2_P];
#pragma unroll
  for (int k = 0; k < F2_P; ++k) {
    int p = t + k * F2_TT;
    px[k] = x[p*3+0]; py[k] = x[p*3+1]; pz[k] = x[p*3+2];
    d[k] = 1e10f;
  }
  float cx = x[0], cy = x[1], cz = x[2];
  if (blockIdx.x == 0 && threadIdx.x == 0) {
    centers[0] = cx; centers[1] = cy; centers[2] = cz;
  }
  for (int r = 1; r < N_GRP; ++r) {
    unsigned long long best = 0ull;
#pragma unroll
    for (int k = 0; k < F2_P; ++k) {
      float e0 = px[k]-cx, e1 = py[k]-cy, e2 = pz[k]-cz;
      float dist = fmaf(e2,e2, fmaf(e1,e1, e0*e0));
      float dn = fminf(d[k], dist);
      d[k] = dn;
      unsigned long long pk = ((unsigned long long)__float_as_uint(dn) << 32)
                            | (0xFFFFFFFFu - (unsigned)(t + k*F2_TT));
      if (pk > best) best = pk;
    }
#pragma unroll
    for (int off = 32; off; off >>= 1) {
      unsigned long long o = __shfl_down(best, off);
      if (o > best) best = o;
    }
    const int wid = threadIdx.x >> 6;
    if ((threadIdx.x & 63) == 0) red[wid] = best;
    __syncthreads();
    if (threadIdx.x == 0) {
#pragma unroll
      for (int w = 1; w < F2_THR/64; ++w) if (red[w] > best) best = red[w];
      atomicMax(&slots[r], best);
      __hip_atomic_fetch_add(&cnts[r], 1u, __ATOMIC_RELEASE, __HIP_MEMORY_SCOPE_AGENT);
      while (__hip_atomic_load(&cnts[r], __ATOMIC_ACQUIRE, __HIP_MEMORY_SCOPE_AGENT) < F2_BLOCKS)
        __builtin_amdgcn_s_sleep(1);
      red[0] = __hip_atomic_load(&slots[r], __ATOMIC_RELAXED, __HIP_MEMORY_SCOPE_AGENT);
    }
    __syncthreads();
    const unsigned long long win = red[0];
    const int widx = (int)(0xFFFFFFFFu - (unsigned int)(win & 0xFFFFFFFFull));
    cx = x[widx*3+0]; cy = x[widx*3+1]; cz = x[widx*3+2];
    if (blockIdx.x == 0 && threadIdx.x == 0) {
      centers[r*3+0] = cx; centers[r*3+1] = cy; centers[r*3+2] = cz;
    }
    __syncthreads();
  }
}

// ---------- Phase 2: per-group exact 32 smallest (proven) ----------
#define TKT 256
#define CAP 3072

__global__ void __launch_bounds__(TKT)
topk_kernel(const float* __restrict__ x, const float* __restrict__ feat,
            const float* __restrict__ centers, float* __restrict__ out)
{
  __shared__ float cv[CAP];
  __shared__ int   ci[CAP];
  __shared__ int   s_cnt;
  __shared__ float s_thr;
  __shared__ float selv[K_NB];
  __shared__ int   seli[K_NB];

  const int g = blockIdx.x, tid = threadIdx.x;
  const float cx = centers[g*3+0], cy = centers[g*3+1], cz = centers[g*3+2];
  const float c2 = fmaf(cz,cz, fmaf(cy,cy, cx*cx));
  if (tid == 0) { s_cnt = 0; s_thr = __builtin_inff(); }
  __syncthreads();

  const int CH = N_PTS / (TKT*8);
  for (int chunk = 0; chunk < CH; ++chunk) {
    const float lthr = s_thr;
#pragma unroll
    for (int k = 0; k < 8; ++k) {
      int p = (chunk*8 + k)*TKT + tid;
      float q0 = x[p*3+0], q1 = x[p*3+1], q2 = x[p*3+2];
      float dot  = fmaf(cz,q2, fmaf(cy,q1, cx*q0));
      float pp   = fmaf(q2,q2, fmaf(q1,q1, q0*q0));
      float dist = fmaf(-2.0f, dot, c2) + pp;
      if (dist <= lthr) {
        int pos = atomicAdd(&s_cnt, 1);
        cv[pos] = dist; ci[pos] = p;
      }
    }
    __syncthreads();
    const int n = s_cnt;
    const bool last = (chunk == CH-1);
    if (n > (CAP - TKT*8) || last) {
      if (tid < 64) {
        for (int it = 0; it < K_NB; ++it) {
          unsigned long long lk = ~0ull;
          for (int j = tid; j < n; j += 64) {
            unsigned long long kk = packMinKey(cv[j], (unsigned)ci[j]);
            if (kk < lk) lk = kk;
          }
#pragma unroll
          for (int off = 32; off; off >>= 1) {
            unsigned long long o = __shfl_xor(lk, off);
            if (o < lk) lk = o;
          }
          const int mi = (int)(unsigned int)(lk & 0xFFFFFFFFull);
          for (int j = tid; j < n; j += 64)
            if (ci[j] == mi) cv[j] = __builtin_inff();
          if (tid == 0) { selv[it] = unpackMinVal(lk); seli[it] = mi; }
        }
      }
      __syncthreads();
      if (!last) {
        if (tid < K_NB) { cv[tid] = selv[tid]; ci[tid] = seli[tid]; }
        if (tid == 0)   { s_cnt = K_NB; s_thr = selv[K_NB-1]; }
        __syncthreads();
      }
    }
  }

  const long base = (long)g * (K_NB*F_DIM);
#pragma unroll
  for (int m = 0; m < (K_NB*F_DIM)/TKT; ++m) {
    int lin = m*TKT + tid;
    int j = lin >> 6, c = lin & 63;
    out[base + lin] = feat[(long)seli[j]*F_DIM + c];
  }
}

// ---------- Phase 3: per-point argmin over 1024 centers (proven) ----------
__global__ void __launch_bounds__(256)
argmin_kernel(const float* __restrict__ x, const float* __restrict__ centers,
              float* __restrict__ outIdx)
{
  __shared__ float scx[N_GRP], scy[N_GRP], scz[N_GRP], sc2[N_GRP];
  for (int i = threadIdx.x; i < N_GRP; i += 256) {
    float a = centers[i*3+0], b = centers[i*3+1], c = centers[i*3+2];
    scx[i]=a; scy[i]=b; scz[i]=c;
    sc2[i] = fmaf(c,c, fmaf(b,b, a*a));
  }
  __syncthreads();
  const int p = blockIdx.x*256 + threadIdx.x;
  const float q0 = x[p*3+0], q1 = x[p*3+1], q2 = x[p*3+2];
  const float pp = fmaf(q2,q2, fmaf(q1,q1, q0*q0));
  float best = __builtin_inff(); int bi = 0;
#pragma unroll 4
  for (int c = 0; c < N_GRP; ++c) {
    float dot  = fmaf(scz[c],q2, fmaf(scy[c],q1, scx[c]*q0));
    float dist = fmaf(-2.0f, dot, sc2[c]) + pp;
    if (dist < best) { best = dist; bi = c; }
  }
  outIdx[p] = (float)bi;
}

// ---------- launch ----------
extern "C" void kernel_launch(void* const* d_in, const int* in_sizes, int n_in,
                              void* d_out, int out_size, void* d_ws, size_t ws_size,
                              hipStream_t stream)
{
  const float* x    = (const float*)d_in[0];
  const float* feat = (const float*)d_in[1];
  float* out = (float*)d_out;
  char* ws = (char*)d_ws;
  unsigned int*       ctrl  = (unsigned int*)ws;                 // [0,256)
  unsigned long long* ring  = (unsigned long long*)(ws + 256);   // 16*8*8 = 1 KiB
  unsigned long long* slots = (unsigned long long*)(ws + 4096);  // 8 KiB (F2)
  unsigned int*       cnts  = (unsigned int*)(ws + 12288);       // 4 KiB (F2)
  float*              ctr   = (float*)(ws + 16384);              // 12 KiB centers

  hipMemsetAsync(ws, 0, 16384, stream);   // re-zero ctrl+ring+slots+cnts each call

  hipLaunchKernelGGL(fps_fast_kernel, dim3(F1_BLOCKS), dim3(F1_THR), 0, stream,
                     x, ctrl, ring, ctr);
  hipLaunchKernelGGL(fps_safe_kernel, dim3(F2_BLOCKS), dim3(F2_THR), 0, stream,
                     x, slots, cnts, ctr, ctrl);
  hipLaunchKernelGGL(topk_kernel, dim3(N_GRP), dim3(TKT), 0, stream, x, feat, ctr, out);
  hipLaunchKernelGGL(argmin_kernel, dim3(N_PTS/256), dim3(256), 0, stream,
                     x, ctr, out + (size_t)N_GRP*K_NB*F_DIM);
}

// Round 7
// 7271.487 us; speedup vs baseline: 3.1336x; 3.1336x over previous
//
#include <hip/hip_runtime.h>
#include <stdint.h>

#define N_PTS   65536
#define N_GRP   1024
#define K_NB    32
#define F_DIM   64

// ---- FPS (single block, chunk-pruned) ----
#define FPS1_THR 1024
#define NCHUNK   1024
#define CPTS     64          // points per chunk
#define NBINS    4096        // 16x16x16 morton grid

// ---- fallback FPS (R1-proven 16-block agent-scope), used only if ws too small ----
#define F2_BLOCKS 16
#define F2_THR    512
#define F2_TT     (F2_BLOCKS*F2_THR)
#define F2_P      (N_PTS / F2_TT)

// ---------- helpers ----------
__device__ __forceinline__ unsigned long long packMinKey(float v, unsigned int idx) {
  unsigned int b = __float_as_uint(v);
  b = (b & 0x80000000u) ? ~b : (b | 0x80000000u);
  return ((unsigned long long)b << 32) | idx;
}
__device__ __forceinline__ float unpackMinVal(unsigned long long k) {
  unsigned int b = (unsigned int)(k >> 32);
  b = (b & 0x80000000u) ? (b & 0x7FFFFFFFu) : ~b;
  return __uint_as_float(b);
}
__device__ __forceinline__ unsigned spread4(unsigned b) {
  return (b & 1u) | ((b & 2u) << 2) | ((b & 4u) << 4) | ((b & 8u) << 6);
}
__device__ __forceinline__ unsigned morton_bid(float a, float b, float c) {
  const float S = 16.0f / 11.0f;        // fixed conservative bbox [-5.5,5.5]^3, clamp handles outliers
  int bx = (int)((a + 5.5f) * S);
  int by = (int)((b + 5.5f) * S);
  int bz = (int)((c + 5.5f) * S);
  bx = min(max(bx, 0), 15); by = min(max(by, 0), 15); bz = min(max(bz, 0), 15);
  return spread4((unsigned)bx) | (spread4((unsigned)by) << 1) | (spread4((unsigned)bz) << 2);
}

// ---------- Phase 1: FPS — one block, one CU, zero cross-block sync ----------
// prep: morton counting-sort into 1024 chunks of 64 (storage [k][chunk] for coalescing)
// rounds: bbox-prune chunks (exact: skip only when min(d,dist) provably no-op),
//         rescan active chunks, u64-key argmax reduce in-block.
__global__ void __launch_bounds__(FPS1_THR)
fps_kernel(const float* __restrict__ x, float4* __restrict__ xs4,
           float* __restrict__ dd, float* __restrict__ centers)
{
  __shared__ unsigned sA[NBINS];
  __shared__ unsigned sB[NBINS];
  __shared__ unsigned long long red[FPS1_THR/64];
  __shared__ float bc[3];
  const int tid = threadIdx.x, lane = tid & 63, wid = tid >> 6;

  // ---- phase 1: histogram
#pragma unroll
  for (int j = 0; j < NBINS/FPS1_THR; ++j) sA[tid + j*FPS1_THR] = 0u;
  __syncthreads();
  for (int i = tid; i < N_PTS; i += FPS1_THR) {
    float a = x[i*3+0], b = x[i*3+1], c = x[i*3+2];
    atomicAdd(&sA[morton_bid(a,b,c)], 1u);
  }
  __syncthreads();

  // ---- phase 2: inclusive scan (ping-pong, 12 passes -> result back in sA), cursor in sB
  {
    unsigned* src = sA; unsigned* dst = sB;
    for (int off = 1; off < NBINS; off <<= 1) {
#pragma unroll
      for (int j = 0; j < NBINS/FPS1_THR; ++j) {
        int i = tid + j*FPS1_THR;
        unsigned v = src[i];
        if (i >= off) v += src[i-off];
        dst[i] = v;
      }
      __syncthreads();
      unsigned* t_ = src; src = dst; dst = t_;
    }
#pragma unroll
    for (int j = 0; j < NBINS/FPS1_THR; ++j) {
      int i = tid + j*FPS1_THR;
      sB[i] = (i == 0) ? 0u : sA[i-1];   // exclusive base = running cursor
    }
    __syncthreads();
  }

  // ---- phase 3: scatter to chunk-interleaved layout; init d
  for (int i = tid; i < N_PTS; i += FPS1_THR) {
    float a = x[i*3+0], b = x[i*3+1], c = x[i*3+2];
    unsigned pos = atomicAdd(&sB[morton_bid(a,b,c)], 1u);
    unsigned sidx = (pos & 63u) * NCHUNK + (pos >> 6);
    xs4[sidx] = make_float4(a, b, c, __uint_as_float((unsigned)i));
    dd[sidx] = 1e10f;                    // INIT_DIST
  }
  __syncthreads();                       // one block = one CU = one L1: stores visible to later loads

  // ---- phase 4: my chunk's bbox
  float lox = 3.0e38f, loy = 3.0e38f, loz = 3.0e38f;
  float hix = -3.0e38f, hiy = -3.0e38f, hiz = -3.0e38f;
  for (int k = 0; k < CPTS; ++k) {
    float4 f = xs4[k*NCHUNK + tid];
    lox = fminf(lox, f.x); hix = fmaxf(hix, f.x);
    loy = fminf(loy, f.y); hiy = fmaxf(hiy, f.y);
    loz = fminf(loz, f.z); hiz = fmaxf(hiz, f.z);
  }

  float cx = x[0], cy = x[1], cz = x[2];         // first centroid = point 0
  if (tid == 0) { centers[0] = cx; centers[1] = cy; centers[2] = cz; }
  unsigned long long ckey = 0ull;                // set on first rescan (round 1 rescans all)
  float cdmax = 1e10f;

  // ---- rounds
  for (int r = 1; r < N_GRP; ++r) {
    // exact-safe prune: skip iff bbox lower bound >= cdmax (margin >> fp rounding)
    float dxl = fmaxf(fmaxf(lox - cx, cx - hix), 0.0f);
    float dyl = fmaxf(fmaxf(loy - cy, cy - hiy), 0.0f);
    float dzl = fmaxf(fmaxf(loz - cz, cz - hiz), 0.0f);
    float b2 = fmaf(dzl, dzl, fmaf(dyl, dyl, dxl*dxl));
    if (b2 < cdmax * 1.0001f) {
      unsigned long long nk = 0ull;
#pragma unroll 8
      for (int k = 0; k < CPTS; ++k) {
        int sidx = k*NCHUNK + tid;
        float4 f = xs4[sidx];
        float dk = dd[sidx];
        float e0 = f.x - cx, e1 = f.y - cy, e2 = f.z - cz;
        float dist = fmaf(e2,e2, fmaf(e1,e1, e0*e0));   // byte-identical to proven chain
        float dn = fminf(dk, dist);
        dd[sidx] = dn;
        unsigned long long kk = ((unsigned long long)__float_as_uint(dn) << 32)
                              | (unsigned long long)(0xFFFFFFFFu - __float_as_uint(f.w));
        if (kk > nk) nk = kk;
      }
      ckey = nk;
      cdmax = __uint_as_float((unsigned)(ckey >> 32));
    }
    // block argmax over 1024 chunk keys
    unsigned long long key = ckey;
#pragma unroll
    for (int off = 32; off; off >>= 1) {
      unsigned long long o = __shfl_xor(key, off);
      if (o > key) key = o;
    }
    if (lane == 0) red[wid] = key;
    __syncthreads();                     // barrier 1
    if (wid == 0) {
      unsigned long long kk2 = (lane < FPS1_THR/64) ? red[lane] : 0ull;
#pragma unroll
      for (int off = 1; off < FPS1_THR/64; off <<= 1) {
        unsigned long long o = __shfl_xor(kk2, off);
        if (o > kk2) kk2 = o;
      }
      if (lane == 0) {
        unsigned orig = 0xFFFFFFFFu - (unsigned)(kk2 & 0xFFFFFFFFull);
        float wx = x[orig*3+0], wy = x[orig*3+1], wz = x[orig*3+2];  // L2-hot
        centers[r*3+0] = wx; centers[r*3+1] = wy; centers[r*3+2] = wz;
        bc[0] = wx; bc[1] = wy; bc[2] = wz;
      }
    }
    __syncthreads();                     // barrier 2
    cx = bc[0]; cy = bc[1]; cz = bc[2];
  }
}

// ---------- fallback FPS (only if ws too small for chunk arrays) ----------
__global__ void __launch_bounds__(F2_THR)
fps_safe_kernel(const float* __restrict__ x, unsigned long long* __restrict__ slots,
                unsigned int* __restrict__ cnts, float* __restrict__ centers)
{
  __shared__ unsigned long long red[F2_THR/64];
  const int t = blockIdx.x * F2_THR + threadIdx.x;
  float px[F2_P], py[F2_P], pz[F2_P], d[F2_P];
#pragma unroll
  for (int k = 0; k < F2_P; ++k) {
    int p = t + k * F2_TT;
    px[k] = x[p*3+0]; py[k] = x[p*3+1]; pz[k] = x[p*3+2];
    d[k] = 1e10f;
  }
  float cx = x[0], cy = x[1], cz = x[2];
  if (blockIdx.x == 0 && threadIdx.x == 0) {
    centers[0] = cx; centers[1] = cy; centers[2] = cz;
  }
  for (int r = 1; r < N_GRP; ++r) {
    unsigned long long best = 0ull;
#pragma unroll
    for (int k = 0; k < F2_P; ++k) {
      float e0 = px[k]-cx, e1 = py[k]-cy, e2 = pz[k]-cz;
      float dist = fmaf(e2,e2, fmaf(e1,e1, e0*e0));
      float dn = fminf(d[k], dist);
      d[k] = dn;
      unsigned long long pk = ((unsigned long long)__float_as_uint(dn) << 32)
                            | (0xFFFFFFFFu - (unsigned)(t + k*F2_TT));
      if (pk > best) best = pk;
    }
#pragma unroll
    for (int off = 32; off; off >>= 1) {
      unsigned long long o = __shfl_down(best, off);
      if (o > best) best = o;
    }
    const int wid = threadIdx.x >> 6;
    if ((threadIdx.x & 63) == 0) red[wid] = best;
    __syncthreads();
    if (threadIdx.x == 0) {
#pragma unroll
      for (int w = 1; w < F2_THR/64; ++w) if (red[w] > best) best = red[w];
      atomicMax(&slots[r], best);
      __hip_atomic_fetch_add(&cnts[r], 1u, __ATOMIC_RELEASE, __HIP_MEMORY_SCOPE_AGENT);
      while (__hip_atomic_load(&cnts[r], __ATOMIC_ACQUIRE, __HIP_MEMORY_SCOPE_AGENT) < F2_BLOCKS)
        __builtin_amdgcn_s_sleep(1);
      red[0] = __hip_atomic_load(&slots[r], __ATOMIC_RELAXED, __HIP_MEMORY_SCOPE_AGENT);
    }
    __syncthreads();
    const unsigned long long win = red[0];
    const int widx = (int)(0xFFFFFFFFu - (unsigned int)(win & 0xFFFFFFFFull));
    cx = x[widx*3+0]; cy = x[widx*3+1]; cz = x[widx*3+2];
    if (blockIdx.x == 0 && threadIdx.x == 0) {
      centers[r*3+0] = cx; centers[r*3+1] = cy; centers[r*3+2] = cz;
    }
    __syncthreads();
  }
}

// ---------- Phase 2: per-group exact 32 smallest (proven) ----------
#define TKT 256
#define CAP 3072

__global__ void __launch_bounds__(TKT)
topk_kernel(const float* __restrict__ x, const float* __restrict__ feat,
            const float* __restrict__ centers, float* __restrict__ out)
{
  __shared__ float cv[CAP];
  __shared__ int   ci[CAP];
  __shared__ int   s_cnt;
  __shared__ float s_thr;
  __shared__ float selv[K_NB];
  __shared__ int   seli[K_NB];

  const int g = blockIdx.x, tid = threadIdx.x;
  const float cx = centers[g*3+0], cy = centers[g*3+1], cz = centers[g*3+2];
  const float c2 = fmaf(cz,cz, fmaf(cy,cy, cx*cx));
  if (tid == 0) { s_cnt = 0; s_thr = __builtin_inff(); }
  __syncthreads();

  const int CH = N_PTS / (TKT*8);
  for (int chunk = 0; chunk < CH; ++chunk) {
    const float lthr = s_thr;
#pragma unroll
    for (int k = 0; k < 8; ++k) {
      int p = (chunk*8 + k)*TKT + tid;
      float q0 = x[p*3+0], q1 = x[p*3+1], q2 = x[p*3+2];
      float dot  = fmaf(cz,q2, fmaf(cy,q1, cx*q0));
      float pp   = fmaf(q2,q2, fmaf(q1,q1, q0*q0));
      float dist = fmaf(-2.0f, dot, c2) + pp;
      if (dist <= lthr) {
        int pos = atomicAdd(&s_cnt, 1);
        cv[pos] = dist; ci[pos] = p;
      }
    }
    __syncthreads();
    const int n = s_cnt;
    const bool last = (chunk == CH-1);
    if (n > (CAP - TKT*8) || last) {
      if (tid < 64) {
        for (int it = 0; it < K_NB; ++it) {
          unsigned long long lk = ~0ull;
          for (int j = tid; j < n; j += 64) {
            unsigned long long kk = packMinKey(cv[j], (unsigned)ci[j]);
            if (kk < lk) lk = kk;
          }
#pragma unroll
          for (int off = 32; off; off >>= 1) {
            unsigned long long o = __shfl_xor(lk, off);
            if (o < lk) lk = o;
          }
          const int mi = (int)(unsigned int)(lk & 0xFFFFFFFFull);
          for (int j = tid; j < n; j += 64)
            if (ci[j] == mi) cv[j] = __builtin_inff();
          if (tid == 0) { selv[it] = unpackMinVal(lk); seli[it] = mi; }
        }
      }
      __syncthreads();
      if (!last) {
        if (tid < K_NB) { cv[tid] = selv[tid]; ci[tid] = seli[tid]; }
        if (tid == 0)   { s_cnt = K_NB; s_thr = selv[K_NB-1]; }
        __syncthreads();
      }
    }
  }

  const long base = (long)g * (K_NB*F_DIM);
#pragma unroll
  for (int m = 0; m < (K_NB*F_DIM)/TKT; ++m) {
    int lin = m*TKT + tid;
    int j = lin >> 6, c = lin & 63;
    out[base + lin] = feat[(long)seli[j]*F_DIM + c];
  }
}

// ---------- Phase 3: per-point argmin over 1024 centers (proven) ----------
__global__ void __launch_bounds__(256)
argmin_kernel(const float* __restrict__ x, const float* __restrict__ centers,
              float* __restrict__ outIdx)
{
  __shared__ float scx[N_GRP], scy[N_GRP], scz[N_GRP], sc2[N_GRP];
  for (int i = threadIdx.x; i < N_GRP; i += 256) {
    float a = centers[i*3+0], b = centers[i*3+1], c = centers[i*3+2];
    scx[i]=a; scy[i]=b; scz[i]=c;
    sc2[i] = fmaf(c,c, fmaf(b,b, a*a));
  }
  __syncthreads();
  const int p = blockIdx.x*256 + threadIdx.x;
  const float q0 = x[p*3+0], q1 = x[p*3+1], q2 = x[p*3+2];
  const float pp = fmaf(q2,q2, fmaf(q1,q1, q0*q0));
  float best = __builtin_inff(); int bi = 0;
#pragma unroll 4
  for (int c = 0; c < N_GRP; ++c) {
    float dot  = fmaf(scz[c],q2, fmaf(scy[c],q1, scx[c]*q0));
    float dist = fmaf(-2.0f, dot, sc2[c]) + pp;
    if (dist < best) { best = dist; bi = c; }
  }
  outIdx[p] = (float)bi;
}

// ---------- launch ----------
extern "C" void kernel_launch(void* const* d_in, const int* in_sizes, int n_in,
                              void* d_out, int out_size, void* d_ws, size_t ws_size,
                              hipStream_t stream)
{
  const float* x    = (const float*)d_in[0];
  const float* feat = (const float*)d_in[1];
  float* out = (float*)d_out;
  char* ws = (char*)d_ws;

  float* ctr = (float*)ws;                                   // 12 KiB centers @ 0
  const size_t DD_OFF  = 65536;                              // 256 KiB d array
  const size_t XS_OFF  = DD_OFF + (size_t)N_PTS*4;           // 1 MiB float4 chunk pts
  const size_t NEED    = XS_OFF + (size_t)N_PTS*16;          // ~1.31 MiB

  if (ws_size >= NEED) {
    float*  dd  = (float*)(ws + DD_OFF);
    float4* xs4 = (float4*)(ws + XS_OFF);
    // no memset needed: kernel writes everything it reads
    hipLaunchKernelGGL(fps_kernel, dim3(1), dim3(FPS1_THR), 0, stream, x, xs4, dd, ctr);
  } else {
    unsigned long long* slots = (unsigned long long*)(ws + 16384);  // 8 KiB
    unsigned int*       cnts  = (unsigned int*)(ws + 24576);        // 4 KiB
    hipMemsetAsync(ws + 16384, 0, 12288, stream);
    hipLaunchKernelGGL(fps_safe_kernel, dim3(F2_BLOCKS), dim3(F2_THR), 0, stream,
                       x, slots, cnts, ctr);
  }
  hipLaunchKernelGGL(topk_kernel, dim3(N_GRP), dim3(TKT), 0, stream, x, feat, ctr, out);
  hipLaunchKernelGGL(argmin_kernel, dim3(N_PTS/256), dim3(256), 0, stream,
                     x, ctr, out + (size_t)N_GRP*K_NB*F_DIM);
}

// Round 8
// 3981.232 us; speedup vs baseline: 5.7233x; 1.8264x over previous
//
#include <hip/hip_runtime.h>
#include <stdint.h>

#define N_PTS   65536
#define N_GRP   1024
#define K_NB    32
#define F_DIM   64

// ---- FPS (single block, compacted chunk-pruned) ----
#define FPS1_THR 1024
#define NCHUNK   1024
#define CPTS     64
#define NBINS    4096        // 16x16x16 morton grid

// ---- fallback FPS (R1-proven agent-scope), only if ws too small ----
#define F2_BLOCKS 16
#define F2_THR    512
#define F2_TT     (F2_BLOCKS*F2_THR)
#define F2_P      (N_PTS / F2_TT)

// ---------- helpers ----------
__device__ __forceinline__ unsigned long long packMinKey(float v, unsigned int idx) {
  unsigned int b = __float_as_uint(v);
  b = (b & 0x80000000u) ? ~b : (b | 0x80000000u);
  return ((unsigned long long)b << 32) | idx;
}
__device__ __forceinline__ float unpackMinVal(unsigned long long k) {
  unsigned int b = (unsigned int)(k >> 32);
  b = (b & 0x80000000u) ? (b & 0x7FFFFFFFu) : ~b;
  return __uint_as_float(b);
}
__device__ __forceinline__ unsigned spread4(unsigned b) {
  return (b & 1u) | ((b & 2u) << 2) | ((b & 4u) << 4) | ((b & 8u) << 6);
}
__device__ __forceinline__ unsigned morton_bid(float a, float b, float c) {
  const float S = 16.0f / 11.0f;
  int bx = (int)((a + 5.5f) * S);
  int by = (int)((b + 5.5f) * S);
  int bz = (int)((c + 5.5f) * S);
  bx = min(max(bx, 0), 15); by = min(max(by, 0), 15); bz = min(max(bz, 0), 15);
  return spread4((unsigned)bx) | (spread4((unsigned)by) << 1) | (spread4((unsigned)bz) << 2);
}

// ---------- Phase 1: FPS — one block; compacted rescan, LDS chunk-max reduce ----------
__global__ void __launch_bounds__(FPS1_THR)
fps_kernel(const float* __restrict__ x, float4* __restrict__ xs4,
           float* __restrict__ dd, float* __restrict__ centers)
{
  __shared__ __align__(16) char smem[32768];
  unsigned* sA = (unsigned*)smem;                           // [0,16K)  scan ping
  unsigned* sB = (unsigned*)(smem + 16384);                 // [16K,32K) scan pong / cursors
  unsigned long long* ckeys = (unsigned long long*)smem;    // [0,8K)   post-sort: chunk max keys
  unsigned* act = (unsigned*)(smem + 8192);                 // [8K,12K) post-sort: active list
  float* bxl = (float*)(smem + 8192);                       // transient bbox arrays [8K,32K)
  float* bxh = bxl + 1024;
  float* byl = bxl + 2048;
  float* byh = bxl + 3072;
  float* bzl = bxl + 4096;
  float* bzh = bxl + 5120;
  __shared__ unsigned long long red[16];
  __shared__ int s_nact;

  const int tid = threadIdx.x, lane = tid & 63, wid = tid >> 6;

  // ---- histogram
#pragma unroll
  for (int j = 0; j < NBINS/FPS1_THR; ++j) sA[tid + j*FPS1_THR] = 0u;
  __syncthreads();
  for (int i = tid; i < N_PTS; i += FPS1_THR) {
    float a = x[i*3+0], b = x[i*3+1], c = x[i*3+2];
    atomicAdd(&sA[morton_bid(a,b,c)], 1u);
  }
  __syncthreads();

  // ---- inclusive scan (Hillis-Steele ping-pong, 12 passes -> result in sA)
  {
    unsigned* src = sA; unsigned* dst = sB;
    for (int off = 1; off < NBINS; off <<= 1) {
#pragma unroll
      for (int j = 0; j < NBINS/FPS1_THR; ++j) {
        int i = tid + j*FPS1_THR;
        unsigned v = src[i];
        if (i >= off) v += src[i-off];
        dst[i] = v;
      }
      __syncthreads();
      unsigned* t_ = src; src = dst; dst = t_;
    }
#pragma unroll
    for (int j = 0; j < NBINS/FPS1_THR; ++j) {
      int i = tid + j*FPS1_THR;
      sB[i] = (i == 0) ? 0u : sA[i-1];    // exclusive cursors
    }
    __syncthreads();
  }

  // ---- scatter: sorted position is the storage index (chunk-major [c][k])
  for (int i = tid; i < N_PTS; i += FPS1_THR) {
    float a = x[i*3+0], b = x[i*3+1], c = x[i*3+2];
    unsigned pos = atomicAdd(&sB[morton_bid(a,b,c)], 1u);
    xs4[pos] = make_float4(a, b, c, __uint_as_float((unsigned)i));
    dd[pos]  = 1e10f;                     // INIT_DIST
  }
  __syncthreads();

  // ---- cooperative per-chunk bbox (wave w handles chunks 64w..64w+63, coalesced)
  for (int cc = 0; cc < 64; ++cc) {
    const int c = wid*64 + cc;
    float4 f = xs4[c*CPTS + lane];
    float xl = f.x, xh = f.x, yl = f.y, yh = f.y, zl = f.z, zh = f.z;
#pragma unroll
    for (int off = 32; off; off >>= 1) {
      xl = fminf(xl, __shfl_xor(xl, off)); xh = fmaxf(xh, __shfl_xor(xh, off));
      yl = fminf(yl, __shfl_xor(yl, off)); yh = fmaxf(yh, __shfl_xor(yh, off));
      zl = fminf(zl, __shfl_xor(zl, off)); zh = fmaxf(zh, __shfl_xor(zh, off));
    }
    if (lane == 0) { bxl[c]=xl; bxh[c]=xh; byl[c]=yl; byh[c]=yh; bzl[c]=zl; bzh[c]=zh; }
  }
  __syncthreads();
  const float rxl = bxl[tid], rxh = bxh[tid];
  const float ryl = byl[tid], ryh = byh[tid];
  const float rzl = bzl[tid], rzh = bzh[tid];
  __syncthreads();                        // bbox area free -> act list

  // init: cdmax=1e10 forces all chunks active in round 1
  ckeys[tid] = ((unsigned long long)__float_as_uint(1e10f) << 32);
  if (tid == 0) s_nact = 0;
  __syncthreads();

  float cx = x[0], cy = x[1], cz = x[2];  // first centroid = point 0
  if (tid == 0) { centers[0] = cx; centers[1] = cy; centers[2] = cz; }

  for (int r = 1; r < N_GRP; ++r) {
    // ---- phase A: bbox prune test (registers + 1 LDS read), ballot-compact
    const float cdmax = __uint_as_float((unsigned)(ckeys[tid] >> 32));
    float dxl = fmaxf(fmaxf(rxl - cx, cx - rxh), 0.0f);
    float dyl = fmaxf(fmaxf(ryl - cy, cy - ryh), 0.0f);
    float dzl = fmaxf(fmaxf(rzl - cz, cz - rzh), 0.0f);
    float b2 = fmaf(dzl, dzl, fmaf(dyl, dyl, dxl*dxl));
    const bool active = b2 < cdmax * 1.0001f;   // exact-safe: margin >> fp rounding
    const unsigned long long bal = __ballot(active);
    int base = 0;
    if (lane == 0) {
      int cnt = __popcll(bal);
      if (cnt) base = atomicAdd(&s_nact, cnt);
    }
    base = __shfl(base, 0);
    if (active) {
      int rank = __popcll(bal & ((1ull << lane) - 1ull));
      act[base + rank] = (unsigned)tid;
    }
    __syncthreads();                       // B1: act list ready

    // ---- phase B: one chunk per wave, round-robin over active list
    const int n = s_nact;
    for (int j = wid; j < n; j += 16) {
      const int c = (int)act[j];
      const int sidx = c*CPTS + lane;
      float4 f = xs4[sidx];
      float dk = dd[sidx];
      float e0 = f.x - cx, e1 = f.y - cy, e2 = f.z - cz;
      float dist = fmaf(e2,e2, fmaf(e1,e1, e0*e0));   // byte-identical chain
      float dn = fminf(dk, dist);
      dd[sidx] = dn;
      unsigned long long kk = ((unsigned long long)__float_as_uint(dn) << 32)
                            | (unsigned long long)(0xFFFFFFFFu - __float_as_uint(f.w));
#pragma unroll
      for (int off = 32; off; off >>= 1) {
        unsigned long long o = __shfl_xor(kk, off);
        if (o > kk) kk = o;
      }
      if (lane == 0) ckeys[c] = kk;
    }
    __syncthreads();                       // B2: ckeys consistent
    if (tid == 0) s_nact = 0;              // consumed above; next atomics after B3

    // ---- block argmax over 1024 chunk keys (LDS + shuffles)
    unsigned long long k = ckeys[tid];
#pragma unroll
    for (int off = 32; off; off >>= 1) {
      unsigned long long o = __shfl_xor(k, off);
      if (o > k) k = o;
    }
    if (lane == 0) red[wid] = k;
    __syncthreads();                       // B3: red ready (also covers s_nact reset)
    unsigned long long k2 = red[lane & 15];  // broadcast reads, no extra barrier
#pragma unroll
    for (int off = 1; off < 16; off <<= 1) {
      unsigned long long o = __shfl_xor(k2, off);
      if (o > k2) k2 = o;
    }
    const unsigned orig = 0xFFFFFFFFu - (unsigned)(k2 & 0xFFFFFFFFull);
    cx = x[orig*3+0]; cy = x[orig*3+1]; cz = x[orig*3+2];  // same-address broadcast load
    if (tid == 0) { centers[r*3+0]=cx; centers[r*3+1]=cy; centers[r*3+2]=cz; }
  }
}

// ---------- fallback FPS (only if ws too small) ----------
__global__ void __launch_bounds__(F2_THR)
fps_safe_kernel(const float* __restrict__ x, unsigned long long* __restrict__ slots,
                unsigned int* __restrict__ cnts, float* __restrict__ centers)
{
  __shared__ unsigned long long red[F2_THR/64];
  const int t = blockIdx.x * F2_THR + threadIdx.x;
  float px[F2_P], py[F2_P], pz[F2_P], d[F2_P];
#pragma unroll
  for (int k = 0; k < F2_P; ++k) {
    int p = t + k * F2_TT;
    px[k] = x[p*3+0]; py[k] = x[p*3+1]; pz[k] = x[p*3+2];
    d[k] = 1e10f;
  }
  float cx = x[0], cy = x[1], cz = x[2];
  if (blockIdx.x == 0 && threadIdx.x == 0) {
    centers[0] = cx; centers[1] = cy; centers[2] = cz;
  }
  for (int r = 1; r < N_GRP; ++r) {
    unsigned long long best = 0ull;
#pragma unroll
    for (int k = 0; k < F2_P; ++k) {
      float e0 = px[k]-cx, e1 = py[k]-cy, e2 = pz[k]-cz;
      float dist = fmaf(e2,e2, fmaf(e1,e1, e0*e0));
      float dn = fminf(d[k], dist);
      d[k] = dn;
      unsigned long long pk = ((unsigned long long)__float_as_uint(dn) << 32)
                            | (0xFFFFFFFFu - (unsigned)(t + k*F2_TT));
      if (pk > best) best = pk;
    }
#pragma unroll
    for (int off = 32; off; off >>= 1) {
      unsigned long long o = __shfl_down(best, off);
      if (o > best) best = o;
    }
    const int wid = threadIdx.x >> 6;
    if ((threadIdx.x & 63) == 0) red[wid] = best;
    __syncthreads();
    if (threadIdx.x == 0) {
#pragma unroll
      for (int w = 1; w < F2_THR/64; ++w) if (red[w] > best) best = red[w];
      atomicMax(&slots[r], best);
      __hip_atomic_fetch_add(&cnts[r], 1u, __ATOMIC_RELEASE, __HIP_MEMORY_SCOPE_AGENT);
      while (__hip_atomic_load(&cnts[r], __ATOMIC_ACQUIRE, __HIP_MEMORY_SCOPE_AGENT) < F2_BLOCKS)
        __builtin_amdgcn_s_sleep(1);
      red[0] = __hip_atomic_load(&slots[r], __ATOMIC_RELAXED, __HIP_MEMORY_SCOPE_AGENT);
    }
    __syncthreads();
    const unsigned long long win = red[0];
    const int widx = (int)(0xFFFFFFFFu - (unsigned int)(win & 0xFFFFFFFFull));
    cx = x[widx*3+0]; cy = x[widx*3+1]; cz = x[widx*3+2];
    if (blockIdx.x == 0 && threadIdx.x == 0) {
      centers[r*3+0] = cx; centers[r*3+1] = cy; centers[r*3+2] = cz;
    }
    __syncthreads();
  }
}

// ---------- Phase 2: per-group exact 32 smallest (proven) ----------
#define TKT 256
#define CAP 3072

__global__ void __launch_bounds__(TKT)
topk_kernel(const float* __restrict__ x, const float* __restrict__ feat,
            const float* __restrict__ centers, float* __restrict__ out)
{
  __shared__ float cv[CAP];
  __shared__ int   ci[CAP];
  __shared__ int   s_cnt;
  __shared__ float s_thr;
  __shared__ float selv[K_NB];
  __shared__ int   seli[K_NB];

  const int g = blockIdx.x, tid = threadIdx.x;
  const float cx = centers[g*3+0], cy = centers[g*3+1], cz = centers[g*3+2];
  const float c2 = fmaf(cz,cz, fmaf(cy,cy, cx*cx));
  if (tid == 0) { s_cnt = 0; s_thr = __builtin_inff(); }
  __syncthreads();

  const int CH = N_PTS / (TKT*8);
  for (int chunk = 0; chunk < CH; ++chunk) {
    const float lthr = s_thr;
#pragma unroll
    for (int k = 0; k < 8; ++k) {
      int p = (chunk*8 + k)*TKT + tid;
      float q0 = x[p*3+0], q1 = x[p*3+1], q2 = x[p*3+2];
      float dot  = fmaf(cz,q2, fmaf(cy,q1, cx*q0));
      float pp   = fmaf(q2,q2, fmaf(q1,q1, q0*q0));
      float dist = fmaf(-2.0f, dot, c2) + pp;
      if (dist <= lthr) {
        int pos = atomicAdd(&s_cnt, 1);
        cv[pos] = dist; ci[pos] = p;
      }
    }
    __syncthreads();
    const int n = s_cnt;
    const bool last = (chunk == CH-1);
    if (n > (CAP - TKT*8) || last) {
      if (tid < 64) {
        for (int it = 0; it < K_NB; ++it) {
          unsigned long long lk = ~0ull;
          for (int j = tid; j < n; j += 64) {
            unsigned long long kk = packMinKey(cv[j], (unsigned)ci[j]);
            if (kk < lk) lk = kk;
          }
#pragma unroll
          for (int off = 32; off; off >>= 1) {
            unsigned long long o = __shfl_xor(lk, off);
            if (o < lk) lk = o;
          }
          const int mi = (int)(unsigned int)(lk & 0xFFFFFFFFull);
          for (int j = tid; j < n; j += 64)
            if (ci[j] == mi) cv[j] = __builtin_inff();
          if (tid == 0) { selv[it] = unpackMinVal(lk); seli[it] = mi; }
        }
      }
      __syncthreads();
      if (!last) {
        if (tid < K_NB) { cv[tid] = selv[tid]; ci[tid] = seli[tid]; }
        if (tid == 0)   { s_cnt = K_NB; s_thr = selv[K_NB-1]; }
        __syncthreads();
      }
    }
  }

  const long base = (long)g * (K_NB*F_DIM);
#pragma unroll
  for (int m = 0; m < (K_NB*F_DIM)/TKT; ++m) {
    int lin = m*TKT + tid;
    int j = lin >> 6, c = lin & 63;
    out[base + lin] = feat[(long)seli[j]*F_DIM + c];
  }
}

// ---------- Phase 3: per-point argmin over 1024 centers (proven) ----------
__global__ void __launch_bounds__(256)
argmin_kernel(const float* __restrict__ x, const float* __restrict__ centers,
              float* __restrict__ outIdx)
{
  __shared__ float scx[N_GRP], scy[N_GRP], scz[N_GRP], sc2[N_GRP];
  for (int i = threadIdx.x; i < N_GRP; i += 256) {
    float a = centers[i*3+0], b = centers[i*3+1], c = centers[i*3+2];
    scx[i]=a; scy[i]=b; scz[i]=c;
    sc2[i] = fmaf(c,c, fmaf(b,b, a*a));
  }
  __syncthreads();
  const int p = blockIdx.x*256 + threadIdx.x;
  const float q0 = x[p*3+0], q1 = x[p*3+1], q2 = x[p*3+2];
  const float pp = fmaf(q2,q2, fmaf(q1,q1, q0*q0));
  float best = __builtin_inff(); int bi = 0;
#pragma unroll 4
  for (int c = 0; c < N_GRP; ++c) {
    float dot  = fmaf(scz[c],q2, fmaf(scy[c],q1, scx[c]*q0));
    float dist = fmaf(-2.0f, dot, sc2[c]) + pp;
    if (dist < best) { best = dist; bi = c; }
  }
  outIdx[p] = (float)bi;
}

// ---------- launch ----------
extern "C" void kernel_launch(void* const* d_in, const int* in_sizes, int n_in,
                              void* d_out, int out_size, void* d_ws, size_t ws_size,
                              hipStream_t stream)
{
  const float* x    = (const float*)d_in[0];
  const float* feat = (const float*)d_in[1];
  float* out = (float*)d_out;
  char* ws = (char*)d_ws;

  float* ctr = (float*)ws;                                   // 12 KiB centers @ 0
  const size_t DD_OFF  = 65536;                              // 256 KiB d array
  const size_t XS_OFF  = DD_OFF + (size_t)N_PTS*4;           // 1 MiB float4 pts
  const size_t NEED    = XS_OFF + (size_t)N_PTS*16;

  if (ws_size >= NEED) {
    float*  dd  = (float*)(ws + DD_OFF);
    float4* xs4 = (float4*)(ws + XS_OFF);
    hipLaunchKernelGGL(fps_kernel, dim3(1), dim3(FPS1_THR), 0, stream, x, xs4, dd, ctr);
  } else {
    unsigned long long* slots = (unsigned long long*)(ws + 16384);
    unsigned int*       cnts  = (unsigned int*)(ws + 24576);
    hipMemsetAsync(ws + 16384, 0, 12288, stream);
    hipLaunchKernelGGL(fps_safe_kernel, dim3(F2_BLOCKS), dim3(F2_THR), 0, stream,
                       x, slots, cnts, ctr);
  }
  hipLaunchKernelGGL(topk_kernel, dim3(N_GRP), dim3(TKT), 0, stream, x, feat, ctr, out);
  hipLaunchKernelGGL(argmin_kernel, dim3(N_PTS/256), dim3(256), 0, stream,
                     x, ctr, out + (size_t)N_GRP*K_NB*F_DIM);
}